// Round 1
// baseline (140.811 us; speedup 1.0000x reference)
//
#include <hip/hip_runtime.h>
#include <hip/hip_bf16.h>

// TextBasedEmbedding: gather char embeddings (vocab=14, d=128) then ragged
// segment-mean over sorted segment_ids. N chars -> T segment means.
//
// Structure (3 dispatches, all plain stores, no atomics, no binary search):
//   1) zero_ws:     zero start[T], end[T] in d_ws (empty segments -> cnt 0 -> out 0)
//   2) mark_bounds: coalesced pass over sorted segment_ids; the unique first/last
//                   char of each segment writes start[s] / end[s]
//   3) seg_mean:    one 64-lane wave per segment; lane owns dims {2l, 2l+1};
//                   indices loaded coalesced by lanes 0..cnt-1, broadcast via
//                   __shfl; embedding table staged in LDS (7 KB).

#define D_MODEL 128
#define VOCAB 14

__global__ void zero_ws_kernel(int* __restrict__ p, int n) {
    int i = blockIdx.x * 256 + threadIdx.x;
    if (i < n) p[i] = 0;
}

__global__ void mark_bounds_kernel(const int* __restrict__ seg, int N,
                                   int* __restrict__ startA, int* __restrict__ endA) {
    int i = blockIdx.x * 256 + threadIdx.x;
    if (i >= N) return;
    int s = seg[i];
    // overlapping neighbor loads are L1/L2 hits; each boundary written once
    if (i == 0 || seg[i - 1] != s) startA[s] = i;
    if (i == N - 1 || seg[i + 1] != s) endA[s] = i + 1;
}

__global__ __launch_bounds__(256) void seg_mean_kernel(
        const float* __restrict__ emb,
        const int* __restrict__ idx,
        const int* __restrict__ startA,
        const int* __restrict__ endA,
        float* __restrict__ out, int T) {
    __shared__ float semb[VOCAB * D_MODEL];   // 7 KB embedding table
    int tid = threadIdx.x;
    for (int i = tid; i < VOCAB * D_MODEL; i += 256) semb[i] = emb[i];
    __syncthreads();

    int wave = tid >> 6;            // 4 waves per block = 4 segments per block
    int lane = tid & 63;
    int t = blockIdx.x * 4 + wave;
    if (t >= T) return;             // no barriers after this point

    int lo = startA[t];
    int hi = endA[t];

    float2 acc = make_float2(0.f, 0.f);
    for (int base = lo; base < hi; base += 64) {
        int rem = hi - base;
        int m = rem < 64 ? rem : 64;
        int myidx = 0;
        if (lane < m) myidx = idx[base + lane];   // one coalesced load for the whole run
        for (int j = 0; j < m; ++j) {
            int ij = __shfl(myidx, j);            // wave-uniform broadcast
            float2 e = *(const float2*)&semb[ij * D_MODEL + 2 * lane];
            acc.x += e.x;
            acc.y += e.y;
        }
    }

    int cnt = hi - lo;
    float inv = 1.0f / (float)(cnt > 0 ? cnt : 1);
    float2 r = make_float2(acc.x * inv, acc.y * inv);
    // lane l -> dims 2l,2l+1: contiguous 512B store per wave
    *(float2*)&out[(size_t)t * D_MODEL + 2 * lane] = r;
}

extern "C" void kernel_launch(void* const* d_in, const int* in_sizes, int n_in,
                              void* d_out, int out_size, void* d_ws, size_t ws_size,
                              hipStream_t stream) {
    const float* char_emb     = (const float*)d_in[0];   // [14,128] fp32
    const int*   char_indices = (const int*)d_in[1];     // [N]
    const int*   segment_ids  = (const int*)d_in[2];     // [N], sorted
    float*       out          = (float*)d_out;           // [T,128] fp32

    int N = in_sizes[1];
    int T = out_size / D_MODEL;

    int* startA = (int*)d_ws;
    int* endA   = startA + T;

    int zn = 2 * T;
    zero_ws_kernel<<<(zn + 255) / 256, 256, 0, stream>>>(startA, zn);
    mark_bounds_kernel<<<(N + 255) / 256, 256, 0, stream>>>(segment_ids, N, startA, endA);
    int nblk = (T + 3) / 4;   // 4 segments (waves) per block
    seg_mean_kernel<<<nblk, 256, 0, stream>>>(char_emb, char_indices, startA, endA, out, T);
}

// Round 2
// 140.489 us; speedup vs baseline: 1.0023x; 1.0023x over previous
//
#include <hip/hip_runtime.h>
#include <hip/hip_bf16.h>

// TextBasedEmbedding: gather char embeddings (vocab=14, d=128) then ragged
// segment-mean over sorted segment_ids. N chars -> T segment means.
//
// Round 2 structure (2 dispatches, no atomics, no LDS in hot loop):
//   1) mark_bounds: int4-vectorized pass over sorted segment_ids. At each
//      transition a->b at position p: bounds[a].end=p, bounds[b].start=p,
//      and any empty segments in (a,b) get start=end=p. Leading empties
//      handled via prev=-1 at p=0; trailing by the thread owning char N-1.
//      No zero-init dispatch needed.
//   2) seg_mean: one wave per segment. Lane owns dims {2l,2l+1}; its 14x2
//      embedding slice lives in 28 VGPRs (loaded once, L1-hit). Per segment:
//      coalesced idx load by lanes 0..cnt-1, then 14 ballots build the vocab
//      histogram in SGPRs -> weighted sum (28 FMA). Zero LDS round-trips,
//      no dependent-latency chain (the round-1 killer: ~12 serialized
//      shfl+ds_read pairs ~ 1300 cyc/segment -> 70 us).

#define D_MODEL 128
#define VOCAB 14

__global__ __launch_bounds__(256) void mark_bounds_kernel(
        const int* __restrict__ seg, int N, int T, int* __restrict__ bounds) {
    int base = (blockIdx.x * 256 + threadIdx.x) * 4;
    if (base >= N) return;

    int vals[4];
    if (base + 3 < N) {
        int4 v = *(const int4*)(seg + base);
        vals[0] = v.x; vals[1] = v.y; vals[2] = v.z; vals[3] = v.w;
    } else {
        for (int k = 0; k < 4; ++k) vals[k] = (base + k < N) ? seg[base + k] : 0;
    }
    int prev = (base == 0) ? -1 : seg[base - 1];

    #pragma unroll
    for (int k = 0; k < 4; ++k) {
        int p = base + k;
        if (p >= N) break;
        int b = vals[k];
        if (b != prev) {
            if (prev >= 0) bounds[2 * prev + 1] = p;       // end of prev
            bounds[2 * b] = p;                             // start of b
            for (int s = prev + 1; s < b; ++s) {           // empty gap (incl. leading)
                bounds[2 * s] = p; bounds[2 * s + 1] = p;
            }
        }
        if (p == N - 1) {                                  // close final + trailing empties
            bounds[2 * b + 1] = N;
            for (int s = b + 1; s < T; ++s) { bounds[2 * s] = N; bounds[2 * s + 1] = N; }
        }
        prev = b;
    }
}

__global__ __launch_bounds__(256) void seg_mean_kernel(
        const float* __restrict__ emb,
        const int* __restrict__ idx,
        const int2* __restrict__ bounds,
        float* __restrict__ out, int T) {
    int lane = threadIdx.x & 63;
    int t = (int)((blockIdx.x * 256 + threadIdx.x) >> 6);  // one segment per wave
    if (t >= T) return;

    // this lane's embedding slice: 14 vocab rows x 2 dims -> 28 VGPRs (L1-hot)
    float2 e[VOCAB];
    #pragma unroll
    for (int v = 0; v < VOCAB; ++v)
        e[v] = *(const float2*)&emb[v * D_MODEL + 2 * lane];

    int2 be = bounds[t];
    int lo = be.x, hi = be.y;

    int cn[VOCAB];
    #pragma unroll
    for (int v = 0; v < VOCAB; ++v) cn[v] = 0;

    for (int b0 = lo; b0 < hi; b0 += 64) {                 // single pass when cnt<=64
        int m = hi - b0; if (m > 64) m = 64;
        int myidx = 0xFF;                                   // sentinel: matches no vocab id
        if (lane < m) myidx = idx[b0 + lane];               // one coalesced load/segment
        #pragma unroll
        for (int v = 0; v < VOCAB; ++v)
            cn[v] += __popcll(__ballot(myidx == v));        // SGPR histogram, no LDS
    }

    float2 acc = make_float2(0.f, 0.f);
    #pragma unroll
    for (int v = 0; v < VOCAB; ++v) {
        float c = (float)cn[v];
        acc.x += c * e[v].x;
        acc.y += c * e[v].y;
    }
    int cnt = hi - lo;
    float inv = 1.0f / (float)(cnt > 0 ? cnt : 1);
    *(float2*)&out[(size_t)t * D_MODEL + 2 * lane] = make_float2(acc.x * inv, acc.y * inv);
}

extern "C" void kernel_launch(void* const* d_in, const int* in_sizes, int n_in,
                              void* d_out, int out_size, void* d_ws, size_t ws_size,
                              hipStream_t stream) {
    const float* char_emb     = (const float*)d_in[0];   // [14,128] fp32
    const int*   char_indices = (const int*)d_in[1];     // [N]
    const int*   segment_ids  = (const int*)d_in[2];     // [N], sorted
    float*       out          = (float*)d_out;           // [T,128] fp32

    int N = in_sizes[1];
    int T = out_size / D_MODEL;

    int* bounds = (int*)d_ws;                            // [T][2] = 1 MB

    int mb_threads = (N + 3) / 4;
    mark_bounds_kernel<<<(mb_threads + 255) / 256, 256, 0, stream>>>(
        segment_ids, N, T, bounds);

    int nblk = (int)(((size_t)T * 64 + 255) / 256);      // 4 segments (waves) per block
    seg_mean_kernel<<<nblk, 256, 0, stream>>>(
        char_emb, char_indices, (const int2*)bounds, out, T);
}

// Round 3
// 105.093 us; speedup vs baseline: 1.3399x; 1.3368x over previous
//
#include <hip/hip_runtime.h>
#include <hip/hip_bf16.h>

// TextBasedEmbedding: gather char embeddings (vocab=14, d=128) then ragged
// segment-mean over sorted segment_ids. N chars -> T segment means.
//
// Round 3: rounds 1 & 2 both pinned at 70us with totally different inner
// loops -> shared limit is the 32768-workgroup grid (~5 cyc/WG = CP dispatch
// rate). Fix: 8 segments per wave, 32 per block -> 4096 WGs, plus 8-way ILP
// on the bounds/idx loads.
//
//   1) mark_bounds: int4 pass over sorted segment_ids; transition writers
//      fill start/end (+ empty-gap fills). No zero-init dispatch needed.
//   2) seg_mean: wave handles 8 consecutive segments. Lane owns dims
//      {2l,2l+1}; 14x2 embedding slice in 28 VGPRs. Per segment: coalesced
//      idx load (lanes 0..cnt-1), 14 ballots -> vocab histogram in SGPRs,
//      weighted sum, 512B contiguous store. No LDS, no atomics.

#define D_MODEL 128
#define VOCAB 14
#define SEGS_PER_WAVE 8
#define WAVES_PER_BLOCK 4
#define SEGS_PER_BLOCK (SEGS_PER_WAVE * WAVES_PER_BLOCK)

__global__ __launch_bounds__(256) void mark_bounds_kernel(
        const int* __restrict__ seg, int N, int T, int* __restrict__ bounds) {
    int base = (blockIdx.x * 256 + threadIdx.x) * 4;
    if (base >= N) return;

    int vals[4];
    if (base + 3 < N) {
        int4 v = *(const int4*)(seg + base);
        vals[0] = v.x; vals[1] = v.y; vals[2] = v.z; vals[3] = v.w;
    } else {
        for (int k = 0; k < 4; ++k) vals[k] = (base + k < N) ? seg[base + k] : 0;
    }
    int prev = (base == 0) ? -1 : seg[base - 1];

    #pragma unroll
    for (int k = 0; k < 4; ++k) {
        int p = base + k;
        if (p >= N) break;
        int b = vals[k];
        if (b != prev) {
            if (prev >= 0) bounds[2 * prev + 1] = p;       // end of prev
            bounds[2 * b] = p;                             // start of b
            for (int s = prev + 1; s < b; ++s) {           // empty gap (incl. leading)
                bounds[2 * s] = p; bounds[2 * s + 1] = p;
            }
        }
        if (p == N - 1) {                                  // close final + trailing empties
            bounds[2 * b + 1] = N;
            for (int s = b + 1; s < T; ++s) { bounds[2 * s] = N; bounds[2 * s + 1] = N; }
        }
        prev = b;
    }
}

__global__ __launch_bounds__(256) void seg_mean_kernel(
        const float* __restrict__ emb,
        const int* __restrict__ idx,
        const int2* __restrict__ bounds,
        float* __restrict__ out, int T) {
    int lane = threadIdx.x & 63;
    int wave = threadIdx.x >> 6;
    int t0 = (blockIdx.x * WAVES_PER_BLOCK + wave) * SEGS_PER_WAVE;
    if (t0 >= T) return;

    // this lane's embedding slice: 14 vocab rows x 2 dims -> 28 VGPRs (L1-hot)
    float2 e[VOCAB];
    #pragma unroll
    for (int v = 0; v < VOCAB; ++v)
        e[v] = *(const float2*)&emb[v * D_MODEL + 2 * lane];

    // 8 independent bounds loads (broadcast), all in flight together
    int lo[SEGS_PER_WAVE], hi[SEGS_PER_WAVE];
    #pragma unroll
    for (int s = 0; s < SEGS_PER_WAVE; ++s) {
        int t = t0 + s;
        int2 be = (t < T) ? bounds[t] : make_int2(0, 0);
        lo[s] = be.x; hi[s] = be.y;
    }

    // 8 independent coalesced idx loads (first <=64 chars of each segment)
    int myidx[SEGS_PER_WAVE];
    #pragma unroll
    for (int s = 0; s < SEGS_PER_WAVE; ++s) {
        int m = hi[s] - lo[s]; if (m > 64) m = 64;
        myidx[s] = 0xFF;                                    // matches no vocab id
        if (lane < m) myidx[s] = idx[lo[s] + lane];
    }

    #pragma unroll
    for (int s = 0; s < SEGS_PER_WAVE; ++s) {
        int t = t0 + s;
        if (t >= T) break;

        int cn[VOCAB];
        #pragma unroll
        for (int v = 0; v < VOCAB; ++v)
            cn[v] = __popcll(__ballot(myidx[s] == v));      // SGPR histogram, no LDS

        // rare overflow: segments longer than 64 chars
        for (int b0 = lo[s] + 64; b0 < hi[s]; b0 += 64) {
            int m = hi[s] - b0; if (m > 64) m = 64;
            int ix = 0xFF;
            if (lane < m) ix = idx[b0 + lane];
            #pragma unroll
            for (int v = 0; v < VOCAB; ++v)
                cn[v] += __popcll(__ballot(ix == v));
        }

        float2 acc = make_float2(0.f, 0.f);
        #pragma unroll
        for (int v = 0; v < VOCAB; ++v) {
            float c = (float)cn[v];
            acc.x += c * e[v].x;
            acc.y += c * e[v].y;
        }
        int cnt = hi[s] - lo[s];
        float inv = 1.0f / (float)(cnt > 0 ? cnt : 1);
        *(float2*)&out[(size_t)t * D_MODEL + 2 * lane] =
            make_float2(acc.x * inv, acc.y * inv);
    }
}

extern "C" void kernel_launch(void* const* d_in, const int* in_sizes, int n_in,
                              void* d_out, int out_size, void* d_ws, size_t ws_size,
                              hipStream_t stream) {
    const float* char_emb     = (const float*)d_in[0];   // [14,128] fp32
    const int*   char_indices = (const int*)d_in[1];     // [N]
    const int*   segment_ids  = (const int*)d_in[2];     // [N], sorted
    float*       out          = (float*)d_out;           // [T,128] fp32

    int N = in_sizes[1];
    int T = out_size / D_MODEL;

    int* bounds = (int*)d_ws;                            // [T][2] = 1 MB

    int mb_threads = (N + 3) / 4;
    mark_bounds_kernel<<<(mb_threads + 255) / 256, 256, 0, stream>>>(
        segment_ids, N, T, bounds);

    int nblk = (T + SEGS_PER_BLOCK - 1) / SEGS_PER_BLOCK;   // 4096 workgroups
    seg_mean_kernel<<<nblk, 256, 0, stream>>>(
        char_emb, char_indices, (const int2*)bounds, out, T);
}

// Round 4
// 101.918 us; speedup vs baseline: 1.3816x; 1.0312x over previous
//
#include <hip/hip_runtime.h>
#include <hip/hip_bf16.h>

// TextBasedEmbedding: gather char embeddings (vocab=14, d=128) then ragged
// segment-mean over sorted segment_ids. N chars -> T segment means.
//
// Round 4: SINGLE fused kernel, no bounds array, no dependent loads.
// Block owns chars [c0, c0+256), one char/thread. Ownership of segments is
// the exact interval (seg[c0-1], seg[c0+255]]  (block 0: prev=-1; the block
// containing char N-1 extends to T-1) -- consecutive blocks tile [0,T)
// including empty segments.
//   Phase 1: per-char LDS atomicAdd into h[slot][vocab] (slot = seg-prev-1,
//            vocab padded 14->16 for b128 reads). Wave 0 alone scans the
//            tail while the boundary segment t_hi continues past the range.
//   Phase 2: waves stride owned segments; 4x ds_read_b128 broadcast the 14
//            counts; weighted sum vs the lane's register-resident 14x2
//            embedding slice; 512B coalesced row store. Empty -> zeros.
// All global loads have linear, data-independent addresses (the R3 killer
// was the bounds->idx dependent chain across an inter-kernel boundary).
// A (never-taken in practice) exact slow path guards spans > 257 ids.

#define D_MODEL 128
#define VOCAB 14
#define CPB 256            // chars per block
#define NSLOT 257          // max distinct ids on fast path: t in (prev, t_hi]
#define HSTRIDE 16         // 14 vocab counts padded to 16 ints

__global__ __launch_bounds__(256) void fused_seg_mean_kernel(
        const float* __restrict__ emb,
        const int* __restrict__ idx,
        const int* __restrict__ seg,
        float* __restrict__ out, int N, int T) {
    __shared__ int h[NSLOT * HSTRIDE];

    const int tid  = threadIdx.x;
    const int c0   = blockIdx.x * CPB;
    const int lane = tid & 63;
    const int wave = tid >> 6;

    const int  prev          = (c0 == 0) ? -1 : seg[c0 - 1];   // same-addr broadcast load
    const int  last          = min(c0 + CPB - 1, N - 1);
    const int  t_hi          = seg[last];
    const bool is_last_block = (last == N - 1);
    const int  t_hi_own      = is_last_block ? (T - 1) : t_hi;
    const int  own           = t_hi_own - prev;                // segments owned
    if (own <= 0) return;                                      // block-uniform

    // lane's embedding slice: dims {2*lane, 2*lane+1} of all 14 vocab rows.
    // Hoisted above the barrier so the loads overlap phase-1 latency.
    float2 e[VOCAB];
    #pragma unroll
    for (int v = 0; v < VOCAB; ++v)
        e[v] = *(const float2*)&emb[v * D_MODEL + 2 * lane];

    const int span_stream = t_hi - prev;   // nonempty ids span (slots needed)

    if (span_stream <= NSLOT) {
        // ------------------------- fast path -------------------------
        for (int i = tid; i < NSLOT * HSTRIDE; i += 256) h[i] = 0;
        __syncthreads();

        int pos = c0 + tid;
        if (pos < N) {
            int s = seg[pos];
            if (s > prev)                                       // head chars of a
                atomicAdd(&h[((s - prev - 1) << 4) + idx[pos]], 1); // continued seg
        }                                                       // belong upstream
        // tail: boundary segment t_hi may continue past the range
        if (wave == 0 && !is_last_block) {
            int p = c0 + CPB;
            while (p < N) {
                int pp = p + lane;
                int ss = (pp < N) ? seg[pp] : 0x7fffffff;
                if (ss == t_hi)
                    atomicAdd(&h[((t_hi - prev - 1) << 4) + idx[pp]], 1);
                if (__shfl(ss, 63) != t_hi) break;              // sorted: done
                p += 64;
            }
        }
        __syncthreads();

        for (int tloc = wave; tloc < own; tloc += 4) {
            float2 acc = make_float2(0.f, 0.f);
            float total = 0.f;
            if (tloc < span_stream) {          // ids > t_hi have no slot (trailing empties)
                const int* hp = &h[tloc << 4];
                int4 a = *(const int4*)(hp + 0);
                int4 b = *(const int4*)(hp + 4);
                int4 c = *(const int4*)(hp + 8);
                int4 d = *(const int4*)(hp + 12);
                int cn[VOCAB] = {a.x, a.y, a.z, a.w, b.x, b.y, b.z, b.w,
                                 c.x, c.y, c.z, c.w, d.x, d.y};
                #pragma unroll
                for (int v = 0; v < VOCAB; ++v) {
                    float f = (float)cn[v];
                    total += f;
                    acc.x += f * e[v].x;
                    acc.y += f * e[v].y;
                }
            }
            float inv = 1.0f / fmaxf(total, 1.0f);
            int t = prev + 1 + tloc;
            *(float2*)&out[(size_t)t * D_MODEL + 2 * lane] =
                make_float2(acc.x * inv, acc.y * inv);
        }
    } else {
        // --------- slow path (pathological: >257-id span; exact) ---------
        for (int tloc = wave; tloc < own; tloc += 4) {
            int t = prev + 1 + tloc;
            int cn[VOCAB];
            #pragma unroll
            for (int v = 0; v < VOCAB; ++v) cn[v] = 0;
            int p = c0;
            while (p < N) {
                int pp = p + lane;
                int ss = (pp < N) ? seg[pp] : 0x7fffffff;
                int ii = (pp < N) ? idx[pp] : 0xff;
                #pragma unroll
                for (int v = 0; v < VOCAB; ++v)
                    cn[v] += __popcll(__ballot(ss == t && ii == v));
                if (__shfl(ss, 63) > t) break;                  // sorted: past t
                p += 64;
            }
            float2 acc = make_float2(0.f, 0.f);
            float total = 0.f;
            #pragma unroll
            for (int v = 0; v < VOCAB; ++v) {
                float f = (float)cn[v];
                total += f;
                acc.x += f * e[v].x;
                acc.y += f * e[v].y;
            }
            float inv = 1.0f / fmaxf(total, 1.0f);
            *(float2*)&out[(size_t)t * D_MODEL + 2 * lane] =
                make_float2(acc.x * inv, acc.y * inv);
        }
    }
}

extern "C" void kernel_launch(void* const* d_in, const int* in_sizes, int n_in,
                              void* d_out, int out_size, void* d_ws, size_t ws_size,
                              hipStream_t stream) {
    const float* char_emb     = (const float*)d_in[0];   // [14,128] fp32
    const int*   char_indices = (const int*)d_in[1];     // [N]
    const int*   segment_ids  = (const int*)d_in[2];     // [N], sorted
    float*       out          = (float*)d_out;           // [T,128] fp32

    int N = in_sizes[1];
    int T = out_size / D_MODEL;

    int nblk = (N + CPB - 1) / CPB;                      // 6144 workgroups
    fused_seg_mean_kernel<<<nblk, 256, 0, stream>>>(
        char_emb, char_indices, segment_ids, out, N, T);
}

// Round 5
// 97.066 us; speedup vs baseline: 1.4507x; 1.0500x over previous
//
#include <hip/hip_runtime.h>
#include <hip/hip_bf16.h>

// TextBasedEmbedding: gather char embeddings (vocab=14, d=128) then ragged
// segment-mean over sorted segment_ids. N chars -> T segment means.
//
// Round 5: R4 structure, coarsened 4x. R2/R3/R4 all resolve to ~2.2-6 ns/WG
// => CP workgroup-dispatch-rate bound (refill demand ~1.7 WG/ns vs CP ~0.46).
// 1024 chars/block -> 1536 WGs = 6 blocks/CU: whole grid resident in one
// generation, dispatch cost ~3us.
//
// Block owns chars [c0, c0+1024). Segment ownership = (seg[c0-1], seg[last]]
// (block 0: prev=-1; block containing char N-1 extends to T-1) -- blocks
// tile [0,T) exactly, empties included.
//   Phase 1: 4 chars/thread via int4 loads; LDS atomicAdd into h[slot][16]
//            (slot = seg-prev-1, vocab 14 padded to 16). Wave 0 scans the
//            tail while boundary segment t_hi continues into later blocks.
//   Phase 2: waves stride owned segments; b128 reads broadcast the counts;
//            weighted sum vs lane's register-resident 14x2 embedding slice;
//            512B coalesced row store. Empty segment -> zeros.
// Exact (never-taken: 21-sigma margin) slow path guards spans > 272 ids.

#define D_MODEL 128
#define VOCAB 14
#define CPB 1024           // chars per block
#define NSLOT 272          // histogram slots (mean span 85, sd ~9)
#define HSTRIDE 16         // 14 vocab counts padded to 16 ints

__global__ __launch_bounds__(256) void fused_seg_mean_kernel(
        const float* __restrict__ emb,
        const int* __restrict__ idx,
        const int* __restrict__ seg,
        float* __restrict__ out, int N, int T) {
    __shared__ int h[NSLOT * HSTRIDE];   // 17408 B

    const int tid  = threadIdx.x;
    const int c0   = blockIdx.x * CPB;
    const int lane = tid & 63;
    const int wave = tid >> 6;

    const int  prev          = (c0 == 0) ? -1 : seg[c0 - 1];   // broadcast load
    const int  last          = min(c0 + CPB - 1, N - 1);
    const int  t_hi          = seg[last];
    const bool is_last_block = (last == N - 1);
    const int  t_hi_own      = is_last_block ? (T - 1) : t_hi;
    const int  own           = t_hi_own - prev;                // segments owned
    if (own <= 0) return;                                      // block-uniform

    // lane's embedding slice: dims {2*lane, 2*lane+1} of all 14 vocab rows.
    float2 e[VOCAB];
    #pragma unroll
    for (int v = 0; v < VOCAB; ++v)
        e[v] = *(const float2*)&emb[v * D_MODEL + 2 * lane];

    const int span_stream = t_hi - prev;   // nonempty-id span (slots needed)

    if (span_stream <= NSLOT) {
        // ------------------------- fast path -------------------------
        for (int i = tid; i < NSLOT * HSTRIDE; i += 256) h[i] = 0;
        __syncthreads();

        int base = c0 + tid * 4;                // 4 chars/thread, 16B coalesced
        int s4[4], i4[4];
        if (base + 3 < N) {
            int4 sv = *(const int4*)(seg + base);
            int4 iv = *(const int4*)(idx + base);
            s4[0] = sv.x; s4[1] = sv.y; s4[2] = sv.z; s4[3] = sv.w;
            i4[0] = iv.x; i4[1] = iv.y; i4[2] = iv.z; i4[3] = iv.w;
        } else {
            for (int k = 0; k < 4; ++k) {
                s4[k] = (base + k < N) ? seg[base + k] : -1;   // -1: skipped below
                i4[k] = (base + k < N) ? idx[base + k] : 0;
            }
        }
        #pragma unroll
        for (int k = 0; k < 4; ++k) {
            int s = s4[k];
            if (s > prev)                                      // chars of a continued
                atomicAdd(&h[((s - prev - 1) << 4) + i4[k]], 1); // seg belong upstream
        }
        // tail: boundary segment t_hi may continue past the block range
        if (wave == 0 && !is_last_block) {
            int p = c0 + CPB;
            while (p < N) {
                int pp = p + lane;
                int ss = (pp < N) ? seg[pp] : 0x7fffffff;
                if (ss == t_hi)
                    atomicAdd(&h[((t_hi - prev - 1) << 4) + idx[pp]], 1);
                if (__shfl(ss, 63) != t_hi) break;             // sorted: done
                p += 64;
            }
        }
        __syncthreads();

        for (int tloc = wave; tloc < own; tloc += 4) {
            float2 acc = make_float2(0.f, 0.f);
            float total = 0.f;
            if (tloc < span_stream) {      // ids > t_hi have no slot (trailing empties)
                const int* hp = &h[tloc << 4];
                int4 a = *(const int4*)(hp + 0);
                int4 b = *(const int4*)(hp + 4);
                int4 c = *(const int4*)(hp + 8);
                int4 d = *(const int4*)(hp + 12);
                int cn[VOCAB] = {a.x, a.y, a.z, a.w, b.x, b.y, b.z, b.w,
                                 c.x, c.y, c.z, c.w, d.x, d.y};
                #pragma unroll
                for (int v = 0; v < VOCAB; ++v) {
                    float f = (float)cn[v];
                    total += f;
                    acc.x += f * e[v].x;
                    acc.y += f * e[v].y;
                }
            }
            float inv = 1.0f / fmaxf(total, 1.0f);
            int t = prev + 1 + tloc;
            *(float2*)&out[(size_t)t * D_MODEL + 2 * lane] =
                make_float2(acc.x * inv, acc.y * inv);
        }
    } else {
        // --------- slow path (pathological: >272-id span; exact) ---------
        for (int tloc = wave; tloc < own; tloc += 4) {
            int t = prev + 1 + tloc;
            int cn[VOCAB];
            #pragma unroll
            for (int v = 0; v < VOCAB; ++v) cn[v] = 0;
            int p = c0;
            while (p < N) {
                int pp = p + lane;
                int ss = (pp < N) ? seg[pp] : 0x7fffffff;
                int ii = (pp < N) ? idx[pp] : 0xff;
                #pragma unroll
                for (int v = 0; v < VOCAB; ++v)
                    cn[v] += __popcll(__ballot(ss == t && ii == v));
                if (__shfl(ss, 63) > t) break;                 // sorted: past t
                p += 64;
            }
            float2 acc = make_float2(0.f, 0.f);
            float total = 0.f;
            #pragma unroll
            for (int v = 0; v < VOCAB; ++v) {
                float f = (float)cn[v];
                total += f;
                acc.x += f * e[v].x;
                acc.y += f * e[v].y;
            }
            float inv = 1.0f / fmaxf(total, 1.0f);
            *(float2*)&out[(size_t)t * D_MODEL + 2 * lane] =
                make_float2(acc.x * inv, acc.y * inv);
        }
    }
}

extern "C" void kernel_launch(void* const* d_in, const int* in_sizes, int n_in,
                              void* d_out, int out_size, void* d_ws, size_t ws_size,
                              hipStream_t stream) {
    const float* char_emb     = (const float*)d_in[0];   // [14,128] fp32
    const int*   char_indices = (const int*)d_in[1];     // [N]
    const int*   segment_ids  = (const int*)d_in[2];     // [N], sorted
    float*       out          = (float*)d_out;           // [T,128] fp32

    int N = in_sizes[1];
    int T = out_size / D_MODEL;

    int nblk = (N + CPB - 1) / CPB;                      // 1536 workgroups
    fused_seg_mean_kernel<<<nblk, 256, 0, stream>>>(
        char_emb, char_indices, segment_ids, out, N, T);
}

// Round 6
// 95.054 us; speedup vs baseline: 1.4814x; 1.0212x over previous
//
#include <hip/hip_runtime.h>
#include <hip/hip_bf16.h>

// TextBasedEmbedding: gather char embeddings (vocab=14, d=128) then ragged
// segment-mean over sorted segment_ids. N chars -> T segment means.
//
// Round 6: R5 structure + half-wave phase 2. R5 accounting: kernel ~30us vs
// 12.5us BW floor; biggest consumers are phase-2 LDS readback (~10us/CU:
// 2040 ds_read_b128 x 12cyc) and per-segment VALU overhead (~7us). Fix:
// lanes 0-31 own segment A, lanes 32-63 segment B, each lane owns 4 dims
// (float4). Every phase-2 wave-op (b128 count reads, cvt, total-adds,
// dwordx4 store) now serves TWO segments -> LDS ~5us, VALU ~5us, both at or
// under the 10.4us store-BW floor. FMA total unchanged (math floor ~3us).
//
// Block owns chars [c0, c0+1024). Segment ownership = (seg[c0-1], seg[last]]
// (block 0: prev=-1; block containing char N-1 extends to T-1) -- blocks
// tile [0,T) exactly, empties included.
//   Phase 1: 4 chars/thread via int4 loads; LDS atomicAdd into h[slot][16]
//            (slot = seg-prev-1, vocab 14 padded to 16). Wave 0 scans the
//            tail while boundary segment t_hi continues into later blocks.
//   Phase 2: wave processes segment pairs; half-wave reads the pair's
//            counts (2-addr b128 broadcast = conflict-free), weighted sum
//            vs lane's register-resident 14x4 embedding slice; 1024B
//            coalesced store per pair. Empty segment -> zeros.
// Exact (never-taken: 21-sigma margin) slow path guards spans > 272 ids.

#define D_MODEL 128
#define VOCAB 14
#define CPB 1024           // chars per block
#define NSLOT 272          // histogram slots (mean span 85, sd ~9)
#define HSTRIDE 16         // 14 vocab counts padded to 16 ints

__global__ __launch_bounds__(256, 4) void fused_seg_mean_kernel(
        const float* __restrict__ emb,
        const int* __restrict__ idx,
        const int* __restrict__ seg,
        float* __restrict__ out, int N, int T) {
    __shared__ int h[NSLOT * HSTRIDE];   // 17408 B

    const int tid  = threadIdx.x;
    const int c0   = blockIdx.x * CPB;
    const int lane = tid & 63;
    const int wave = tid >> 6;
    const int sub  = lane & 31;          // lane-in-half
    const int half = lane >> 5;          // 0: segment p, 1: segment p+1

    const int  prev          = (c0 == 0) ? -1 : seg[c0 - 1];   // broadcast load
    const int  last          = min(c0 + CPB - 1, N - 1);
    const int  t_hi          = seg[last];
    const bool is_last_block = (last == N - 1);
    const int  t_hi_own      = is_last_block ? (T - 1) : t_hi;
    const int  own           = t_hi_own - prev;                // segments owned
    if (own <= 0) return;                                      // block-uniform

    // lane's embedding slice: dims {4*sub .. 4*sub+3} of all 14 vocab rows
    // (halves load identical values; 56 VGPRs).
    float4 e4[VOCAB];
    #pragma unroll
    for (int v = 0; v < VOCAB; ++v)
        e4[v] = *(const float4*)&emb[v * D_MODEL + 4 * sub];

    const int span_stream = t_hi - prev;   // nonempty-id span (slots needed)

    if (span_stream <= NSLOT) {
        // ------------------------- fast path -------------------------
        for (int i = tid; i < NSLOT * HSTRIDE; i += 256) h[i] = 0;
        __syncthreads();

        int base = c0 + tid * 4;                // 4 chars/thread, 16B coalesced
        int s4[4], i4[4];
        if (base + 3 < N) {
            int4 sv = *(const int4*)(seg + base);
            int4 iv = *(const int4*)(idx + base);
            s4[0] = sv.x; s4[1] = sv.y; s4[2] = sv.z; s4[3] = sv.w;
            i4[0] = iv.x; i4[1] = iv.y; i4[2] = iv.z; i4[3] = iv.w;
        } else {
            for (int k = 0; k < 4; ++k) {
                s4[k] = (base + k < N) ? seg[base + k] : -1;   // -1: skipped below
                i4[k] = (base + k < N) ? idx[base + k] : 0;
            }
        }
        #pragma unroll
        for (int k = 0; k < 4; ++k) {
            int s = s4[k];
            if (s > prev)                                      // chars of a continued
                atomicAdd(&h[((s - prev - 1) << 4) + i4[k]], 1); // seg belong upstream
        }
        // tail: boundary segment t_hi may continue past the block range
        if (wave == 0 && !is_last_block) {
            int p = c0 + CPB;
            while (p < N) {
                int pp = p + lane;
                int ss = (pp < N) ? seg[pp] : 0x7fffffff;
                if (ss == t_hi)
                    atomicAdd(&h[((t_hi - prev - 1) << 4) + idx[pp]], 1);
                if (__shfl(ss, 63) != t_hi) break;             // sorted: done
                p += 64;
            }
        }
        __syncthreads();

        // wave handles segment pair {p, p+1}; half-wave owns one segment
        for (int p = wave * 2; p < own; p += 8) {
            int tloc = p + half;
            float4 acc = make_float4(0.f, 0.f, 0.f, 0.f);
            float total = 0.f;
            if (tloc < span_stream) {      // ids > t_hi have no slot (trailing empties)
                const int* hp = &h[tloc << 4];
                int4 a = *(const int4*)(hp + 0);
                int4 b = *(const int4*)(hp + 4);
                int4 c = *(const int4*)(hp + 8);
                int4 d = *(const int4*)(hp + 12);
                int cn[VOCAB] = {a.x, a.y, a.z, a.w, b.x, b.y, b.z, b.w,
                                 c.x, c.y, c.z, c.w, d.x, d.y};
                #pragma unroll
                for (int v = 0; v < VOCAB; ++v) {
                    float f = (float)cn[v];
                    total += f;
                    acc.x += f * e4[v].x;
                    acc.y += f * e4[v].y;
                    acc.z += f * e4[v].z;
                    acc.w += f * e4[v].w;
                }
            }
            if (tloc < own) {
                float inv = 1.0f / fmaxf(total, 1.0f);
                int t = prev + 1 + tloc;
                *(float4*)&out[(size_t)t * D_MODEL + 4 * sub] =
                    make_float4(acc.x * inv, acc.y * inv, acc.z * inv, acc.w * inv);
            }
        }
    } else {
        // --------- slow path (pathological: >272-id span; exact) ---------
        for (int p = wave * 2; p < own; p += 8) {
            int tloc = p + half;
            bool active = tloc < own;
            int t = prev + 1 + tloc;
            int cn[VOCAB];
            #pragma unroll
            for (int v = 0; v < VOCAB; ++v) cn[v] = 0;
            int q = c0;
            while (q < N) {
                int qq = q + sub;                 // both halves scan same 32 chars
                int ss = (qq < N) ? seg[qq] : 0x7fffffff;
                int ii = (qq < N) ? idx[qq] : 0xff;
                #pragma unroll
                for (int v = 0; v < VOCAB; ++v) {
                    unsigned long long m = __ballot(active && ss == t && ii == v);
                    cn[v] += __popcll(half ? (m >> 32) : (m & 0xffffffffull));
                }
                // sorted: window's max seg (lane 31) past both pair members -> done
                if (__shfl(ss, 31) > prev + 2 + p) break;
                q += 32;
            }
            float4 acc = make_float4(0.f, 0.f, 0.f, 0.f);
            float total = 0.f;
            #pragma unroll
            for (int v = 0; v < VOCAB; ++v) {
                float f = (float)cn[v];
                total += f;
                acc.x += f * e4[v].x;
                acc.y += f * e4[v].y;
                acc.z += f * e4[v].z;
                acc.w += f * e4[v].w;
            }
            if (active) {
                float inv = 1.0f / fmaxf(total, 1.0f);
                *(float4*)&out[(size_t)t * D_MODEL + 4 * sub] =
                    make_float4(acc.x * inv, acc.y * inv, acc.z * inv, acc.w * inv);
            }
        }
    }
}

extern "C" void kernel_launch(void* const* d_in, const int* in_sizes, int n_in,
                              void* d_out, int out_size, void* d_ws, size_t ws_size,
                              hipStream_t stream) {
    const float* char_emb     = (const float*)d_in[0];   // [14,128] fp32
    const int*   char_indices = (const int*)d_in[1];     // [N]
    const int*   segment_ids  = (const int*)d_in[2];     // [N], sorted
    float*       out          = (float*)d_out;           // [T,128] fp32

    int N = in_sizes[1];
    int T = out_size / D_MODEL;

    int nblk = (N + CPB - 1) / CPB;                      // 1536 workgroups
    fused_seg_mean_kernel<<<nblk, 256, 0, stream>>>(
        char_emb, char_indices, segment_ids, out, N, T);
}